// Round 1
// baseline (134.873 us; speedup 1.0000x reference)
//
#include <hip/hip_runtime.h>

// SelfmixLayer: out = TP(a,b)+TP(b,a) + k⊙x, where a=s1⊙x, b=s2⊙x (⊙ with
// [1,3,5]-repeat expansion over the 9-component irrep layout [l=0 | l=1 | l=2]).
// Cross(a1,b1)+cross(b1,a1)=0; sym_l2 terms double. Per row (b,n,f):
//   A=2 p0 q0, B=2 p1 q1, C=2 p2 q2, D=2(p0 q1+q0 p1), E=2(p0 q2+q0 p2)
//   out0   = A x0^2 + B(x1^2+x2^2+x3^2) + C(x4^2+...+x8^2) + k0 x0
//   out1-3 = (D x0 + k1) x_i
//   out4   = E x0 x4 + B*2 x1 x2            + k2 x4
//   out5   = E x0 x5 + B*2 x2 x3            + k2 x5
//   out6   = E x0 x6 + B*(2x3^2-x1^2-x2^2)/sqrt3 + k2 x6
//   out7   = E x0 x7 + B*2 x1 x3            + k2 x7
//   out8   = E x0 x8 + B*(x1^2-x2^2)        + k2 x8
//
// Memory-bound map. 4 rows/thread = 144 B (16B-aligned) -> dwordx4 in/out.

#define INV_SQRT3 0.57735026918962576f

__global__ __launch_bounds__(256) void selfmix_kernel(
    const float* __restrict__ x,
    const float* __restrict__ s1,
    const float* __restrict__ s2,
    const float* __restrict__ kk,
    float* __restrict__ out,
    long long n_rows)
{
    long long t = (long long)blockIdx.x * blockDim.x + threadIdx.x;
    long long row0 = t * 4;
    if (row0 >= n_rows) return;

    // ---- load 4 rows (36 floats, 144 B, 16B aligned) ----
    const float4* __restrict__ xin = (const float4*)(x + row0 * 9);
    float xs[36];
#pragma unroll
    for (int i = 0; i < 9; ++i) {
        float4 v = xin[i];
        xs[4 * i + 0] = v.x; xs[4 * i + 1] = v.y;
        xs[4 * i + 2] = v.z; xs[4 * i + 3] = v.w;
    }

    // ---- load coefficients for 4 consecutive features (no wrap: 4 | 256) ----
    int f0 = (int)(row0 & 255);                 // row0 % F, F == 256
    const float4* __restrict__ p1v = (const float4*)(s1 + 3 * f0);
    const float4* __restrict__ p2v = (const float4*)(s2 + 3 * f0);
    const float4* __restrict__ pkv = (const float4*)(kk + 3 * f0);
    float c1[12], c2[12], ck[12];
#pragma unroll
    for (int i = 0; i < 3; ++i) {
        float4 a = p1v[i];
        c1[4 * i + 0] = a.x; c1[4 * i + 1] = a.y; c1[4 * i + 2] = a.z; c1[4 * i + 3] = a.w;
        float4 b = p2v[i];
        c2[4 * i + 0] = b.x; c2[4 * i + 1] = b.y; c2[4 * i + 2] = b.z; c2[4 * i + 3] = b.w;
        float4 c = pkv[i];
        ck[4 * i + 0] = c.x; ck[4 * i + 1] = c.y; ck[4 * i + 2] = c.z; ck[4 * i + 3] = c.w;
    }

    float os[36];
#pragma unroll
    for (int r = 0; r < 4; ++r) {
        const float x0 = xs[9 * r + 0];
        const float x1 = xs[9 * r + 1];
        const float x2 = xs[9 * r + 2];
        const float x3 = xs[9 * r + 3];
        const float x4 = xs[9 * r + 4];
        const float x5 = xs[9 * r + 5];
        const float x6 = xs[9 * r + 6];
        const float x7 = xs[9 * r + 7];
        const float x8 = xs[9 * r + 8];

        const float p0 = c1[3 * r + 0], p1 = c1[3 * r + 1], p2 = c1[3 * r + 2];
        const float q0 = c2[3 * r + 0], q1 = c2[3 * r + 1], q2 = c2[3 * r + 2];
        const float k0 = ck[3 * r + 0], k1 = ck[3 * r + 1], k2 = ck[3 * r + 2];

        const float A = 2.0f * p0 * q0;
        const float B = 2.0f * p1 * q1;
        const float C = 2.0f * p2 * q2;
        const float D = 2.0f * (p0 * q1 + q0 * p1);
        const float E = 2.0f * (p0 * q2 + q0 * p2);

        const float n1 = x1 * x1 + x2 * x2 + x3 * x3;
        const float n2 = x4 * x4 + x5 * x5 + x6 * x6 + x7 * x7 + x8 * x8;

        os[9 * r + 0] = A * x0 * x0 + B * n1 + C * n2 + k0 * x0;

        const float d1 = D * x0 + k1;
        os[9 * r + 1] = d1 * x1;
        os[9 * r + 2] = d1 * x2;
        os[9 * r + 3] = d1 * x3;

        const float e0 = E * x0;
        os[9 * r + 4] = e0 * x4 + B * (2.0f * x1 * x2) + k2 * x4;
        os[9 * r + 5] = e0 * x5 + B * (2.0f * x2 * x3) + k2 * x5;
        os[9 * r + 6] = e0 * x6 + B * ((2.0f * x3 * x3 - x1 * x1 - x2 * x2) * INV_SQRT3) + k2 * x6;
        os[9 * r + 7] = e0 * x7 + B * (2.0f * x1 * x3) + k2 * x7;
        os[9 * r + 8] = e0 * x8 + B * (x1 * x1 - x2 * x2) + k2 * x8;
    }

    // ---- store 4 rows ----
    float4* __restrict__ outv = (float4*)(out + row0 * 9);
#pragma unroll
    for (int i = 0; i < 9; ++i) {
        outv[i] = make_float4(os[4 * i + 0], os[4 * i + 1], os[4 * i + 2], os[4 * i + 3]);
    }
}

extern "C" void kernel_launch(void* const* d_in, const int* in_sizes, int n_in,
                              void* d_out, int out_size, void* d_ws, size_t ws_size,
                              hipStream_t stream) {
    const float* x  = (const float*)d_in[0];   // mo_features (B,N,F,9) f32
    const float* s1 = (const float*)d_in[1];   // (F,3)
    const float* s2 = (const float*)d_in[2];   // (F,3)
    const float* kk = (const float*)d_in[3];   // (F,3)
    float* out = (float*)d_out;

    long long n_rows = (long long)in_sizes[0] / 9;       // 4,194,304
    long long n_threads = (n_rows + 3) / 4;              // 4 rows per thread
    int block = 256;
    long long grid = (n_threads + block - 1) / block;    // 4096

    selfmix_kernel<<<(dim3)(unsigned)grid, block, 0, stream>>>(x, s1, s2, kk, out, n_rows);
}

// Round 2
// 64.053 us; speedup vs baseline: 2.1056x; 2.1056x over previous
//
#include <hip/hip_runtime.h>

// SelfmixLayer: out = TP(a,b)+TP(b,a) + k⊙x, a=s1⊙x, b=s2⊙x ([1,3,5]-repeat).
// Cross terms cancel, sym_l2 doubles. Per row (9 floats), with per-feature
// coefficients A=2p0q0, B=2p1q1, C=2p2q2, D=2(p0q1+q0p1), E=2(p0q2+q0p2):
//   out0   = A x0^2 + B|x1..3|^2 + C|x4..8|^2 + k0 x0
//   out1-3 = (D x0 + k1) x_i
//   out4-8 = E x0 x_j + B*sym(x1..3)_j + k2 x_j
//
// Memory-bound map (302 MB round trip -> ~48 us floor at 6.3 TB/s).
// R0 lesson: per-thread-row stores caused 2x WRITE_SIZE amplification
// (144 B inter-lane stride -> partial-line evictions). Fix: LDS-staged tiles
// so every global access is lane-consecutive float4.
//
// Tile = 1024 rows = 9216 floats = 36 KB LDS. Block 256 threads:
//  phase 1: 9 coalesced float4 loads/thread -> LDS
//  phase 2: thread t computes rows {t, t+256, t+512, t+768}; scalar LDS reads
//           at float-stride 9 (odd) -> conflict-free; rows share feature f=tid
//           so coefficients are computed once per thread.
//  phase 3: in-place LDS update, then 9 coalesced float4 stores.

#define INV_SQRT3 0.57735026918962576f
#define ROWS_PER_TILE 1024
#define TILE_F4 2304   // 1024 rows * 9 floats / 4

__global__ __launch_bounds__(256) void selfmix_kernel(
    const float4* __restrict__ x4,
    const float* __restrict__ s1,
    const float* __restrict__ s2,
    const float* __restrict__ kk,
    float4* __restrict__ out4,
    long long n_f4)   // total float4 count
{
    __shared__ float lds[ROWS_PER_TILE * 9];
    float4* __restrict__ lds4 = (float4*)lds;

    const int tid = threadIdx.x;
    const long long base4 = (long long)blockIdx.x * TILE_F4;

    // ---- per-feature coefficients (f == tid, F == 256, tile multiple of F) ----
    const float p0 = s1[3 * tid + 0], p1 = s1[3 * tid + 1], p2 = s1[3 * tid + 2];
    const float q0 = s2[3 * tid + 0], q1 = s2[3 * tid + 1], q2 = s2[3 * tid + 2];
    const float k0 = kk[3 * tid + 0], k1 = kk[3 * tid + 1], k2 = kk[3 * tid + 2];
    const float A = 2.0f * p0 * q0;
    const float B = 2.0f * p1 * q1;
    const float C = 2.0f * p2 * q2;
    const float D = 2.0f * (p0 * q1 + q0 * p1);
    const float E = 2.0f * (p0 * q2 + q0 * p2);

    // ---- phase 1: coalesced global -> LDS ----
#pragma unroll
    for (int i = 0; i < 9; ++i) {
        long long g = base4 + i * 256 + tid;
        if (g < n_f4) lds4[i * 256 + tid] = x4[g];
    }
    __syncthreads();

    // ---- phase 2: compute 4 rows in-place ----
#pragma unroll
    for (int j = 0; j < 4; ++j) {
        float* __restrict__ p = lds + 9 * (tid + 256 * j);
        const float x0 = p[0], x1 = p[1], x2 = p[2], x3 = p[3], x4v = p[4],
                    x5 = p[5], x6 = p[6], x7 = p[7], x8 = p[8];

        const float n1 = x1 * x1 + x2 * x2 + x3 * x3;
        const float n2 = x4v * x4v + x5 * x5 + x6 * x6 + x7 * x7 + x8 * x8;

        p[0] = A * x0 * x0 + B * n1 + C * n2 + k0 * x0;

        const float d1 = D * x0 + k1;
        p[1] = d1 * x1;
        p[2] = d1 * x2;
        p[3] = d1 * x3;

        const float e0 = E * x0;
        p[4] = e0 * x4v + B * (2.0f * x1 * x2) + k2 * x4v;
        p[5] = e0 * x5 + B * (2.0f * x2 * x3) + k2 * x5;
        p[6] = e0 * x6 + B * ((2.0f * x3 * x3 - x1 * x1 - x2 * x2) * INV_SQRT3) + k2 * x6;
        p[7] = e0 * x7 + B * (2.0f * x1 * x3) + k2 * x7;
        p[8] = e0 * x8 + B * (x1 * x1 - x2 * x2) + k2 * x8;
    }
    __syncthreads();

    // ---- phase 3: coalesced LDS -> global ----
#pragma unroll
    for (int i = 0; i < 9; ++i) {
        long long g = base4 + i * 256 + tid;
        if (g < n_f4) out4[g] = lds4[i * 256 + tid];
    }
}

extern "C" void kernel_launch(void* const* d_in, const int* in_sizes, int n_in,
                              void* d_out, int out_size, void* d_ws, size_t ws_size,
                              hipStream_t stream) {
    const float4* x4 = (const float4*)d_in[0];   // mo_features (B,N,F,9) f32
    const float* s1  = (const float*)d_in[1];    // (F,3)
    const float* s2  = (const float*)d_in[2];    // (F,3)
    const float* kk  = (const float*)d_in[3];    // (F,3)
    float4* out4 = (float4*)d_out;

    long long n_floats = (long long)in_sizes[0];       // 37,748,736
    long long n_f4 = n_floats / 4;                     // 9,437,184
    long long n_tiles = (n_f4 + TILE_F4 - 1) / TILE_F4; // 4096

    selfmix_kernel<<<(dim3)(unsigned)n_tiles, 256, 0, stream>>>(
        x4, s1, s2, kk, out4, n_f4);
}

// Round 3
// 60.877 us; speedup vs baseline: 2.2155x; 1.0522x over previous
//
#include <hip/hip_runtime.h>

// SelfmixLayer: out = TP(a,b)+TP(b,a) + k⊙x, a=s1⊙x, b=s2⊙x ([1,3,5]-repeat).
// Cross terms cancel, sym_l2 doubles. Per row (9 floats), with per-feature
// coefficients A=2p0q0, B=2p1q1, C=2p2q2, D=2(p0q1+q0p1), E=2(p0q2+q0p2):
//   out0   = A x0^2 + B|x1..3|^2 + C|x4..8|^2 + k0 x0
//   out1-3 = (D x0 + k1) x_i
//   out4-8 = E x0 x_j + B*sym(x1..3)_j + k2 x_j
//
// Memory-bound map (302 MB logical round trip -> ~48 us floor at 6.3 TB/s).
// R0 lesson: per-thread-row stores -> 2x WRITE_SIZE (partial-line evictions).
// R1 lesson: 36 KB LDS tile capped occupancy at 4 blocks/CU (38% occ,
//            2.5 TB/s, latency-bound). Fix: 512-row tile = 18 KB LDS ->
//            8 blocks/CU = 100% occupancy cap.
//
// Tile = 512 rows = 4608 floats = 1152 float4 = 18 KB LDS. Block 256:
//  phase 1: 4.5 coalesced float4 loads/thread -> LDS (5th iter half-active)
//  phase 2: thread t computes rows {t, t+256} in-place; both rows have
//           feature f = t (512 = 2*F), so coefficients computed once.
//           Scalar LDS reads at float-stride 9 (odd) -> conflict-free.
//  phase 3: 4.5 coalesced float4 stores.

#define INV_SQRT3 0.57735026918962576f
#define ROWS_PER_TILE 512
#define TILE_F4 1152   // 512 rows * 9 floats / 4

__global__ __launch_bounds__(256, 8) void selfmix_kernel(
    const float4* __restrict__ x4,
    const float* __restrict__ s1,
    const float* __restrict__ s2,
    const float* __restrict__ kk,
    float4* __restrict__ out4)
{
    __shared__ float lds[ROWS_PER_TILE * 9];
    float4* __restrict__ lds4 = (float4*)lds;

    const int tid = threadIdx.x;
    const long long base4 = (long long)blockIdx.x * TILE_F4;

    // ---- per-feature coefficients (f == tid for both rows this thread owns) ----
    const float p0 = s1[3 * tid + 0], p1 = s1[3 * tid + 1], p2 = s1[3 * tid + 2];
    const float q0 = s2[3 * tid + 0], q1 = s2[3 * tid + 1], q2 = s2[3 * tid + 2];
    const float k0 = kk[3 * tid + 0], k1 = kk[3 * tid + 1], k2 = kk[3 * tid + 2];
    const float A = 2.0f * p0 * q0;
    const float B = 2.0f * p1 * q1;
    const float C = 2.0f * p2 * q2;
    const float D = 2.0f * (p0 * q1 + q0 * p1);
    const float E = 2.0f * (p0 * q2 + q0 * p2);

    // ---- phase 1: coalesced global -> LDS (1152 f4, 256 threads, 4.5 each) ----
#pragma unroll
    for (int i = 0; i < 5; ++i) {
        int idx = i * 256 + tid;
        if (idx < TILE_F4) lds4[idx] = x4[base4 + idx];
    }
    __syncthreads();

    // ---- phase 2: compute 2 rows in-place ----
#pragma unroll
    for (int j = 0; j < 2; ++j) {
        float* __restrict__ p = lds + 9 * (tid + 256 * j);
        const float x0 = p[0], x1 = p[1], x2 = p[2], x3 = p[3], x4v = p[4],
                    x5 = p[5], x6 = p[6], x7 = p[7], x8 = p[8];

        const float n1 = x1 * x1 + x2 * x2 + x3 * x3;
        const float n2 = x4v * x4v + x5 * x5 + x6 * x6 + x7 * x7 + x8 * x8;

        p[0] = A * x0 * x0 + B * n1 + C * n2 + k0 * x0;

        const float d1 = D * x0 + k1;
        p[1] = d1 * x1;
        p[2] = d1 * x2;
        p[3] = d1 * x3;

        const float e0 = E * x0;
        p[4] = e0 * x4v + B * (2.0f * x1 * x2) + k2 * x4v;
        p[5] = e0 * x5 + B * (2.0f * x2 * x3) + k2 * x5;
        p[6] = e0 * x6 + B * ((2.0f * x3 * x3 - x1 * x1 - x2 * x2) * INV_SQRT3) + k2 * x6;
        p[7] = e0 * x7 + B * (2.0f * x1 * x3) + k2 * x7;
        p[8] = e0 * x8 + B * (x1 * x1 - x2 * x2) + k2 * x8;
    }
    __syncthreads();

    // ---- phase 3: coalesced LDS -> global ----
#pragma unroll
    for (int i = 0; i < 5; ++i) {
        int idx = i * 256 + tid;
        if (idx < TILE_F4) out4[base4 + idx] = lds4[idx];
    }
}

extern "C" void kernel_launch(void* const* d_in, const int* in_sizes, int n_in,
                              void* d_out, int out_size, void* d_ws, size_t ws_size,
                              hipStream_t stream) {
    const float4* x4 = (const float4*)d_in[0];   // mo_features (B,N,F,9) f32
    const float* s1  = (const float*)d_in[1];    // (F,3)
    const float* s2  = (const float*)d_in[2];    // (F,3)
    const float* kk  = (const float*)d_in[3];    // (F,3)
    float4* out4 = (float4*)d_out;

    long long n_floats = (long long)in_sizes[0];        // 37,748,736
    long long n_f4 = n_floats / 4;                      // 9,437,184
    long long n_tiles = (n_f4 + TILE_F4 - 1) / TILE_F4; // 8192 (exact)

    selfmix_kernel<<<(dim3)(unsigned)n_tiles, 256, 0, stream>>>(
        x4, s1, s2, kk, out4);
}

// Round 5
// 49.710 us; speedup vs baseline: 2.7132x; 1.2246x over previous
//
#include <hip/hip_runtime.h>

// SelfmixLayer: out = TP(a,b)+TP(b,a) + k⊙x, a=s1⊙x, b=s2⊙x ([1,3,5]-repeat).
// Cross terms cancel, sym_l2 doubles. Per row (9 floats), per-feature coeffs
// A=2p0q0, B=2p1q1, C=2p2q2, D=2(p0q1+q0p1), E=2(p0q2+q0p2):
//   out0   = A x0^2 + B|x1..3|^2 + C|x4..8|^2 + k0 x0
//   out1-3 = (D x0 + k1) x_i
//   out4-8 = E x0 x_j + B*sym(x1..3)_j + k2 x_j
//
// R0: per-thread-row stores -> 2x WRITE_SIZE. R1: LDS staging fixed writes.
// R2: 18 KB tile -> 8 blocks/CU, but load->barrier->compute->store still
//     serializes HBM latency once per block (61 us = 4.96 TB/s logical).
// R3 fix: persistent blocks (8 tiles each), double-buffered LDS, prefetch of
// tile t+1 via global_load_lds issued BEFORE compute of tile t, RAW s_barrier
// (__syncthreads would emit vmcnt(0) and drain the prefetch - m97 lesson).
// R4: compile fix - nontemporal_store needs ext_vector_type, not float4.

#define INV_SQRT3 0.57735026918962576f
#define TILE_F4 1152            // 512 rows * 9 floats / 4
#define TILES_PER_BLOCK 8

typedef float f32x4 __attribute__((ext_vector_type(4)));

__device__ __forceinline__ void gload16(const float4* g, const float4* l) {
    __builtin_amdgcn_global_load_lds(
        (const __attribute__((address_space(1))) void*)g,
        (__attribute__((address_space(3))) void*)l,
        16, 0, 0);
}

__global__ __launch_bounds__(256) void selfmix_kernel(
    const float4* __restrict__ x4,
    const float* __restrict__ s1,
    const float* __restrict__ s2,
    const float* __restrict__ kk,
    float4* __restrict__ out4,
    long long n_tiles)
{
    __shared__ float4 buf[2][TILE_F4];   // 36 KB -> 4 blocks/CU

    const int tid = threadIdx.x;
    const int wbase = tid & ~63;         // wave-uniform LDS base (HW adds lane*16)

    // ---- per-feature coefficients (f == tid for every row this thread owns:
    //      tiles are 512 rows, 512 = 2*F, rows {tid, tid+256} both have f=tid) ----
    const float p0 = s1[3 * tid + 0], p1 = s1[3 * tid + 1], p2 = s1[3 * tid + 2];
    const float q0 = s2[3 * tid + 0], q1 = s2[3 * tid + 1], q2 = s2[3 * tid + 2];
    const float k0 = kk[3 * tid + 0], k1 = kk[3 * tid + 1], k2 = kk[3 * tid + 2];
    const float A = 2.0f * p0 * q0;
    const float B = 2.0f * p1 * q1;
    const float C = 2.0f * p2 * q2;
    const float D = 2.0f * (p0 * q1 + q0 * p1);
    const float E = 2.0f * (p0 * q2 + q0 * p2);

    const long long tile0 = (long long)blockIdx.x * TILES_PER_BLOCK;

    // ---- prologue: prefetch tile0 -> buf[0] (global_load_lds, 16B/lane) ----
    {
        const float4* g = x4 + tile0 * TILE_F4;
#pragma unroll
        for (int i = 0; i < 4; ++i)
            gload16(&g[i * 256 + tid], &buf[0][i * 256 + wbase]);
        if (tid < 128)                                  // wave-uniform branch
            gload16(&g[4 * 256 + tid], &buf[0][4 * 256 + wbase]);
    }

    int cur = 0;
    for (int it = 0; it < TILES_PER_BLOCK; ++it) {
        // tile `it` data needed NOW: wait my DMA (and my old stores), then sync.
        asm volatile("s_waitcnt vmcnt(0)" ::: "memory");
        __builtin_amdgcn_s_barrier();

        // issue prefetch of tile it+1 into the other buffer; stays in flight
        // across compute+store below (raw barriers never drain vmcnt).
        if (tile0 + it + 1 < n_tiles && it + 1 < TILES_PER_BLOCK) {
            const float4* g = x4 + (tile0 + it + 1) * TILE_F4;
#pragma unroll
            for (int i = 0; i < 4; ++i)
                gload16(&g[i * 256 + tid], &buf[cur ^ 1][i * 256 + wbase]);
            if (tid < 128)
                gload16(&g[4 * 256 + tid], &buf[cur ^ 1][4 * 256 + wbase]);
        }

        // ---- compute 2 rows in place (scalar LDS, stride 9 = conflict-free) ----
        float* lf = (float*)&buf[cur][0];
#pragma unroll
        for (int j = 0; j < 2; ++j) {
            float* p = lf + 9 * (tid + 256 * j);
            const float x0 = p[0], x1 = p[1], x2 = p[2], x3 = p[3], x4v = p[4],
                        x5 = p[5], x6 = p[6], x7 = p[7], x8 = p[8];

            const float n1 = x1 * x1 + x2 * x2 + x3 * x3;
            const float n2 = x4v * x4v + x5 * x5 + x6 * x6 + x7 * x7 + x8 * x8;

            p[0] = A * x0 * x0 + B * n1 + C * n2 + k0 * x0;

            const float d1 = D * x0 + k1;
            p[1] = d1 * x1;
            p[2] = d1 * x2;
            p[3] = d1 * x3;

            const float e0 = E * x0;
            p[4] = e0 * x4v + B * (2.0f * x1 * x2) + k2 * x4v;
            p[5] = e0 * x5 + B * (2.0f * x2 * x3) + k2 * x5;
            p[6] = e0 * x6 + B * ((2.0f * x3 * x3 - x1 * x1 - x2 * x2) * INV_SQRT3) + k2 * x6;
            p[7] = e0 * x7 + B * (2.0f * x1 * x3) + k2 * x7;
            p[8] = e0 * x8 + B * (x1 * x1 - x2 * x2) + k2 * x8;
        }
        asm volatile("s_waitcnt lgkmcnt(0)" ::: "memory");  // my LDS writes done
        __builtin_amdgcn_s_barrier();                        // everyone's done

        // ---- coalesced LDS -> global, nontemporal (don't evict input from L3) ----
        f32x4* o = (f32x4*)(out4 + (tile0 + it) * TILE_F4);
        const f32x4* lv = (const f32x4*)&buf[cur][0];
#pragma unroll
        for (int i = 0; i < 4; ++i) {
            f32x4 v = lv[i * 256 + tid];
            __builtin_nontemporal_store(v, &o[i * 256 + tid]);
        }
        if (tid < 128) {
            f32x4 v = lv[4 * 256 + tid];
            __builtin_nontemporal_store(v, &o[4 * 256 + tid]);
        }
        // no trailing barrier needed: next iter's vmcnt(0)+barrier guarantees
        // all threads' stores (hence their LDS reads) completed before the
        // buffer is re-filled by DMA.

        cur ^= 1;
    }
}

extern "C" void kernel_launch(void* const* d_in, const int* in_sizes, int n_in,
                              void* d_out, int out_size, void* d_ws, size_t ws_size,
                              hipStream_t stream) {
    const float4* x4 = (const float4*)d_in[0];   // mo_features (B,N,F,9) f32
    const float* s1  = (const float*)d_in[1];    // (F,3)
    const float* s2  = (const float*)d_in[2];    // (F,3)
    const float* kk  = (const float*)d_in[3];    // (F,3)
    float4* out4 = (float4*)d_out;

    long long n_floats = (long long)in_sizes[0];        // 37,748,736
    long long n_f4 = n_floats / 4;                      // 9,437,184
    long long n_tiles = (n_f4 + TILE_F4 - 1) / TILE_F4; // 8192 (exact)
    long long n_blocks = (n_tiles + TILES_PER_BLOCK - 1) / TILES_PER_BLOCK; // 1024

    selfmix_kernel<<<(dim3)(unsigned)n_blocks, 256, 0, stream>>>(
        x4, s1, s2, kk, out4, n_tiles);
}